// Round 9
// baseline (109.543 us; speedup 1.0000x reference)
//
#include <hip/hip_runtime.h>
#include <hip/hip_bf16.h>
#include <hip/hip_fp8.h>

#define N 8192
#define D 200
#define KP 232      // fp8 row stride BYTES: 58 dwords, gcd(58,32)=2 -> <=2-way LDS aliasing
#define NSTEP 7     // 7 * 32 = 224 K fed to MFMA
#define NB 64       // 8192 / 128 tiles per dim
#define NBLK 512    // 32 row-pairs x 16 strips
#define NPART (NBLK * 4)
#define PANEL (128 * KP)           // 29696 B, contiguous in global AND in LDS

typedef float f32x4 __attribute__((ext_vector_type(4)));
#define AS3 __attribute__((address_space(3)))
#define AS1 __attribute__((address_space(1)))

// ---- prep: cast to fp8 e4m3 (padded to KP), row norms from fp8-decoded ----
__global__ __launch_bounds__(256) void prep_kernel(
    const float* __restrict__ x, const int* __restrict__ labels,
    unsigned char* __restrict__ xb, float* __restrict__ sq,
    int* __restrict__ lab) {
  int wave = blockIdx.x * 4 + (threadIdx.x >> 6);  // 2048 waves
  int lane = threadIdx.x & 63;
  int k0 = lane * 4;
#pragma unroll
  for (int rr = 0; rr < 4; ++rr) {                 // 4 rows per wave, stride 2048
    int row = wave + rr * 2048;
    const float* xr = x + (size_t)row * D;
    unsigned char* xbr = xb + (size_t)row * KP;
    float4 f = {0.f, 0.f, 0.f, 0.f};
    if (k0 < D) f = *(const float4*)(xr + k0);     // lane<50 fully in-bounds
    float s = 0.f;
    unsigned char q[4];
    float ff[4] = {f.x, f.y, f.z, f.w};
#pragma unroll
    for (int c = 0; c < 4; ++c) {
      float v = (k0 + c < D) ? ff[c] : 0.f;
      __hip_fp8_e4m3 h(v);                         // OCP e4m3 RNE
      q[c] = h.__x;
      float fb = (float)h;
      s += fb * fb;                                // norm of the fp8-rounded row
    }
    if (k0 < KP) *(uchar4*)(xbr + k0) = *(uchar4*)q; // lanes 0..57 (56,57 zeros)
#pragma unroll
    for (int m = 32; m; m >>= 1) s += __shfl_xor(s, m);
    if (lane == 0) {
      sq[row] = s;
      lab[row] = labels[row];
    }
  }
}

// --- multi-tile fp8 MFMA (R6 structure) + fused last-block final reduce ---
__global__ __launch_bounds__(256) void gram_kernel(
    const unsigned char* __restrict__ xb, const float* __restrict__ sq,
    const int* __restrict__ lab, double* __restrict__ partial,
    unsigned* __restrict__ ticket, float* __restrict__ out) {
  __shared__ __align__(16) unsigned char sA[PANEL];
  __shared__ __align__(16) unsigned char sB[PANEL];

  const int t = threadIdx.x;
  const int b = blockIdx.x;
  const int q = b >> 4, s = b & 15;                // row-pair q / strip s
  const int row2 = 63 - q;
  const int n1 = 64 - q;                           // tiles in row q; row2 adds q+1; 65 total

  const int wid = t >> 6, lane = t & 63;
  const int col = lane & 15, quad = lane >> 4;
  const int waveM = (wid >> 1) * 64, waveN = (wid & 1) * 64;

  auto stage = [&](const unsigned char* g, unsigned char* sh) {
#pragma unroll
    for (int c = 0; c < 7; ++c) {
      int off = c * 4096 + t * 16;
      __builtin_amdgcn_global_load_lds((const AS1 void*)(g + off),
                                       (AS3 void*)(sh + off), 16, 0, 0);
    }
    if (t < 64) {
      int off = 28672 + t * 16;
      __builtin_amdgcn_global_load_lds((const AS1 void*)(g + off),
                                       (AS3 void*)(sh + off), 16, 0, 0);
    }
  };

  int idx = s;                                     // strided walk: s, s+16, ... < 65
  int bi = (idx < n1) ? q : row2;
  int bj = (idx < n1) ? q + idx : row2 + (idx - n1);
  stage(xb + (size_t)bi * PANEL, sA);
  stage(xb + (size_t)bj * PANEL, sB);
  __syncthreads();

  float tot = 0.f;
  while (true) {
    // ---- K-loop on (bi, bj) ----
    f32x4 acc[4][4] = {};
#pragma unroll
    for (int step = 0; step < NSTEP; ++step) {
      long a[4], bf[4];
#pragma unroll
      for (int mi = 0; mi < 4; ++mi)
        a[mi] = *(const long*)(sA + (waveM + mi * 16 + col) * KP + step * 32 + quad * 8);
#pragma unroll
      for (int ni = 0; ni < 4; ++ni)
        bf[ni] = *(const long*)(sB + (waveN + ni * 16 + col) * KP + step * 32 + quad * 8);
#pragma unroll
      for (int mi = 0; mi < 4; ++mi)
#pragma unroll
        for (int ni = 0; ni < 4; ++ni)
          acc[mi][ni] = __builtin_amdgcn_mfma_f32_16x16x32_fp8_fp8(
              a[mi], bf[ni], acc[mi][ni], 0, 0, 0);
    }
    __syncthreads();                               // all waves done reading sA/sB

    // ---- issue next tile's staging BEFORE the epilogue (overlap) ----
    const int nidx = idx + 16;
    const bool more = (nidx < 65);
    int nbi = 0, nbj = 0;
    if (more) {
      nbi = (nidx < n1) ? q : row2;
      nbj = (nidx < n1) ? q + nidx : row2 + (nidx - n1);
      if (nbi != bi) stage(xb + (size_t)nbi * PANEL, sA);   // once per block at most
      stage(xb + (size_t)nbj * PANEL, sB);
    }

    // ---- epilogue (overlaps staging): D[m = quad*4 + r][n = col] ----
    const int i0 = bi * 128 + waveM, j0 = bj * 128 + waveN;
    int labj[4];
    float sqj[4];
#pragma unroll
    for (int ni = 0; ni < 4; ++ni) {
      int j = j0 + ni * 16 + col;
      labj[ni] = lab[j];
      sqj[ni] = sq[j];
    }
    float rs = 0.f;
    if (bi != bj) {
#pragma unroll
      for (int mi = 0; mi < 4; ++mi) {
#pragma unroll
        for (int r = 0; r < 4; ++r) {
          int i = i0 + mi * 16 + quad * 4 + r;
          float sqi = sq[i];
          int li = lab[i];
#pragma unroll
          for (int ni = 0; ni < 4; ++ni) {
            float g = acc[mi][ni][r];
            float d2 = fmaxf(fmaf(-2.f, g, sqi + sqj[ni]), 0.f);
            float dist = __builtin_amdgcn_sqrtf(d2);
            rs += (li == labj[ni]) ? dist : -dist;
          }
        }
      }
      tot += 2.f * rs;                             // mirror tile not launched
    } else {
#pragma unroll
      for (int mi = 0; mi < 4; ++mi) {
#pragma unroll
        for (int r = 0; r < 4; ++r) {
          int i = i0 + mi * 16 + quad * 4 + r;
          float sqi = sq[i];
          int li = lab[i];
#pragma unroll
          for (int ni = 0; ni < 4; ++ni) {
            int j = j0 + ni * 16 + col;
            float g = acc[mi][ni][r];
            float d2 = fmaxf(fmaf(-2.f, g, sqi + sqj[ni]), 0.f);
            float dist = __builtin_amdgcn_sqrtf(d2);
            float c = (li == labj[ni]) ? dist : -dist;
            rs += (i == j) ? 0.f : c;
          }
        }
      }
      tot += rs;
    }

    if (!more) break;
    bi = nbi; bj = nbj; idx = nidx;
    __syncthreads();                               // staging (vmcnt) drained here
  }

#pragma unroll
  for (int m = 32; m; m >>= 1) tot += __shfl_xor(tot, m);
  if (lane == 0) partial[b * 4 + wid] = (double)tot;

  // ---- last block finishes: sum all partials, write the mean ----
  __shared__ unsigned lastflag;
  __shared__ double wsum[4];
  __threadfence();                                 // publish partial[] before ticket
  if (t == 0) {
    unsigned old = atomicAdd(ticket, 1u);
    lastflag = (old == NBLK - 1) ? 1u : 0u;
  }
  __syncthreads();
  if (lastflag) {
    __threadfence();                               // acquire: see others' partial[]
    double sm = 0.0;
#pragma unroll
    for (int c = 0; c < NPART / 256; ++c) sm += partial[t + c * 256];
#pragma unroll
    for (int m = 32; m; m >>= 1) sm += __shfl_xor(sm, m);
    if (lane == 0) wsum[wid] = sm;
    __syncthreads();
    if (t == 0)
      out[0] = (float)((wsum[0] + wsum[1] + wsum[2] + wsum[3]) / (double)N);
  }
}

// ---- tiny init: zero the ticket (ws is re-poisoned before every launch) ----
__global__ void init_kernel(unsigned* ticket) { *ticket = 0u; }

extern "C" void kernel_launch(void* const* d_in, const int* in_sizes, int n_in,
                              void* d_out, int out_size, void* d_ws, size_t ws_size,
                              hipStream_t stream) {
  const float* x = (const float*)d_in[0];
  const int* labels = (const int*)d_in[1];
  char* ws = (char*)d_ws;
  unsigned char* xb = (unsigned char*)ws;                            // N*KP = 1.9 MB
  float* sq = (float*)(ws + (size_t)N * KP);                         // N*4
  int* lab = (int*)(ws + (size_t)N * KP + (size_t)N * 4);            // N*4
  double* partial = (double*)(ws + (size_t)N * KP + (size_t)N * 8);  // NPART*8
  unsigned* ticket = (unsigned*)(ws + (size_t)N * KP + (size_t)N * 8 + (size_t)NPART * 8);
  float* out = (float*)d_out;

  init_kernel<<<1, 1, 0, stream>>>(ticket);
  prep_kernel<<<NBLK, 256, 0, stream>>>(x, labels, xb, sq, lab);
  gram_kernel<<<NBLK, 256, 0, stream>>>(xb, sq, lab, partial, ticket, out);
}

// Round 10
// 85.222 us; speedup vs baseline: 1.2854x; 1.2854x over previous
//
#include <hip/hip_runtime.h>
#include <hip/hip_bf16.h>
#include <hip/hip_fp8.h>

#define N 8192
#define D 200
#define KP 232      // fp8 row stride BYTES: 58 dwords, gcd(58,32)=2 -> <=2-way LDS aliasing
#define NSTEP 7     // 7 * 32 = 224 K fed to MFMA
#define NB 64       // 8192 / 128 tiles per dim
#define NBLK 512    // 32 row-pairs x 16 strips
#define NPART (NBLK * 4)
#define PANEL (128 * KP)           // 29696 B, contiguous in global AND in LDS

typedef float f32x4 __attribute__((ext_vector_type(4)));
#define AS3 __attribute__((address_space(3)))
#define AS1 __attribute__((address_space(1)))

// ---- prep: cast to fp8 e4m3 (padded to KP), row norms from fp8-decoded ----
__global__ __launch_bounds__(256) void prep_kernel(
    const float* __restrict__ x, const int* __restrict__ labels,
    unsigned char* __restrict__ xb, float* __restrict__ sq,
    int* __restrict__ lab) {
  int wave = blockIdx.x * 4 + (threadIdx.x >> 6);  // 2048 waves
  int lane = threadIdx.x & 63;
  int k0 = lane * 4;
#pragma unroll
  for (int rr = 0; rr < 4; ++rr) {                 // 4 rows per wave, stride 2048
    int row = wave + rr * 2048;
    const float* xr = x + (size_t)row * D;
    unsigned char* xbr = xb + (size_t)row * KP;
    float4 f = {0.f, 0.f, 0.f, 0.f};
    if (k0 < D) f = *(const float4*)(xr + k0);     // lane<50 fully in-bounds
    float s = 0.f;
    unsigned char q[4];
    float ff[4] = {f.x, f.y, f.z, f.w};
#pragma unroll
    for (int c = 0; c < 4; ++c) {
      float v = (k0 + c < D) ? ff[c] : 0.f;
      __hip_fp8_e4m3 h(v);                         // OCP e4m3 RNE
      q[c] = h.__x;
      float fb = (float)h;
      s += fb * fb;                                // norm of the fp8-rounded row
    }
    if (k0 < KP) *(uchar4*)(xbr + k0) = *(uchar4*)q; // lanes 0..57 (56,57 zeros)
#pragma unroll
    for (int m = 32; m; m >>= 1) s += __shfl_xor(s, m);
    if (lane == 0) {
      sq[row] = s;
      lab[row] = labels[row];
    }
  }
}

// --- multi-tile fp8 MFMA (R6 structure): A-panel reuse, B staging overlapped
//     with epilogue; strip start rotated so 5-tile blocks never co-reside ---
__global__ __launch_bounds__(256) void gram_kernel(
    const unsigned char* __restrict__ xb, const float* __restrict__ sq,
    const int* __restrict__ lab, double* __restrict__ partial) {
  __shared__ __align__(16) unsigned char sA[PANEL];
  __shared__ __align__(16) unsigned char sB[PANEL];

  const int t = threadIdx.x;
  const int b = blockIdx.x;
  const int q = b >> 4, s = b & 15;                // row-pair q / strip s
  const int row2 = 63 - q;
  const int n1 = 64 - q;                           // tiles in row q; row2 adds q+1; 65 total
  const int start = (q + s) & 15;                  // rotate: 5-tile block at b=15q+16

  const int wid = t >> 6, lane = t & 63;
  const int col = lane & 15, quad = lane >> 4;
  const int waveM = (wid >> 1) * 64, waveN = (wid & 1) * 64;

  auto stage = [&](const unsigned char* g, unsigned char* sh) {
#pragma unroll
    for (int c = 0; c < 7; ++c) {
      int off = c * 4096 + t * 16;
      __builtin_amdgcn_global_load_lds((const AS1 void*)(g + off),
                                       (AS3 void*)(sh + off), 16, 0, 0);
    }
    if (t < 64) {
      int off = 28672 + t * 16;
      __builtin_amdgcn_global_load_lds((const AS1 void*)(g + off),
                                       (AS3 void*)(sh + off), 16, 0, 0);
    }
  };

  int idx = start;                                 // strided walk: start, start+16, ... < 65
  int bi = (idx < n1) ? q : row2;
  int bj = (idx < n1) ? q + idx : row2 + (idx - n1);
  stage(xb + (size_t)bi * PANEL, sA);
  stage(xb + (size_t)bj * PANEL, sB);
  __syncthreads();

  float tot = 0.f;
  while (true) {
    // ---- K-loop on (bi, bj) ----
    f32x4 acc[4][4] = {};
#pragma unroll
    for (int step = 0; step < NSTEP; ++step) {
      long a[4], bf[4];
#pragma unroll
      for (int mi = 0; mi < 4; ++mi)
        a[mi] = *(const long*)(sA + (waveM + mi * 16 + col) * KP + step * 32 + quad * 8);
#pragma unroll
      for (int ni = 0; ni < 4; ++ni)
        bf[ni] = *(const long*)(sB + (waveN + ni * 16 + col) * KP + step * 32 + quad * 8);
#pragma unroll
      for (int mi = 0; mi < 4; ++mi)
#pragma unroll
        for (int ni = 0; ni < 4; ++ni)
          acc[mi][ni] = __builtin_amdgcn_mfma_f32_16x16x32_fp8_fp8(
              a[mi], bf[ni], acc[mi][ni], 0, 0, 0);
    }
    __syncthreads();                               // all waves done reading sA/sB

    // ---- issue next tile's staging BEFORE the epilogue (overlap) ----
    const int nidx = idx + 16;
    const bool more = (nidx < 65);
    int nbi = 0, nbj = 0;
    if (more) {
      nbi = (nidx < n1) ? q : row2;
      nbj = (nidx < n1) ? q + nidx : row2 + (nidx - n1);
      if (nbi != bi) stage(xb + (size_t)nbi * PANEL, sA);   // once per block at most
      stage(xb + (size_t)nbj * PANEL, sB);
    }

    // ---- epilogue (overlaps staging): D[m = quad*4 + r][n = col] ----
    const int i0 = bi * 128 + waveM, j0 = bj * 128 + waveN;
    int labj[4];
    float sqj[4];
#pragma unroll
    for (int ni = 0; ni < 4; ++ni) {
      int j = j0 + ni * 16 + col;
      labj[ni] = lab[j];
      sqj[ni] = sq[j];
    }
    float rs = 0.f;
    if (bi != bj) {
#pragma unroll
      for (int mi = 0; mi < 4; ++mi) {
#pragma unroll
        for (int r = 0; r < 4; ++r) {
          int i = i0 + mi * 16 + quad * 4 + r;
          float sqi = sq[i];
          int li = lab[i];
#pragma unroll
          for (int ni = 0; ni < 4; ++ni) {
            float g = acc[mi][ni][r];
            float d2 = fmaxf(fmaf(-2.f, g, sqi + sqj[ni]), 0.f);
            float dist = __builtin_amdgcn_sqrtf(d2);
            rs += (li == labj[ni]) ? dist : -dist;
          }
        }
      }
      tot += 2.f * rs;                             // mirror tile not launched
    } else {
#pragma unroll
      for (int mi = 0; mi < 4; ++mi) {
#pragma unroll
        for (int r = 0; r < 4; ++r) {
          int i = i0 + mi * 16 + quad * 4 + r;
          float sqi = sq[i];
          int li = lab[i];
#pragma unroll
          for (int ni = 0; ni < 4; ++ni) {
            int j = j0 + ni * 16 + col;
            float g = acc[mi][ni][r];
            float d2 = fmaxf(fmaf(-2.f, g, sqi + sqj[ni]), 0.f);
            float dist = __builtin_amdgcn_sqrtf(d2);
            float c = (li == labj[ni]) ? dist : -dist;
            rs += (i == j) ? 0.f : c;
          }
        }
      }
      tot += rs;
    }

    if (!more) break;
    bi = nbi; bj = nbj; idx = nidx;
    __syncthreads();                               // staging (vmcnt) drained here
  }

#pragma unroll
  for (int m = 32; m; m >>= 1) tot += __shfl_xor(tot, m);
  if (lane == 0) partial[b * 4 + wid] = (double)tot;
}

// ---------------- final mean ----------------
__global__ __launch_bounds__(256) void reduce_kernel(
    const double* __restrict__ partial, float* __restrict__ out) {
  __shared__ double wsum[4];
  double s = 0.0;
  for (int i = threadIdx.x; i < NPART; i += 256) s += partial[i];
#pragma unroll
  for (int m = 32; m; m >>= 1) s += __shfl_xor(s, m);
  if ((threadIdx.x & 63) == 0) wsum[threadIdx.x >> 6] = s;
  __syncthreads();
  if (threadIdx.x == 0)
    out[0] = (float)((wsum[0] + wsum[1] + wsum[2] + wsum[3]) / (double)N);
}

extern "C" void kernel_launch(void* const* d_in, const int* in_sizes, int n_in,
                              void* d_out, int out_size, void* d_ws, size_t ws_size,
                              hipStream_t stream) {
  const float* x = (const float*)d_in[0];
  const int* labels = (const int*)d_in[1];
  char* ws = (char*)d_ws;
  unsigned char* xb = (unsigned char*)ws;                            // N*KP = 1.9 MB
  float* sq = (float*)(ws + (size_t)N * KP);                         // N*4
  int* lab = (int*)(ws + (size_t)N * KP + (size_t)N * 4);            // N*4
  double* partial = (double*)(ws + (size_t)N * KP + (size_t)N * 8);  // NPART*8
  float* out = (float*)d_out;

  prep_kernel<<<NBLK, 256, 0, stream>>>(x, labels, xb, sq, lab);
  gram_kernel<<<NBLK, 256, 0, stream>>>(xb, sq, lab, partial);
  reduce_kernel<<<1, 256, 0, stream>>>(partial, out);
}

// Round 11
// 82.554 us; speedup vs baseline: 1.3269x; 1.0323x over previous
//
#include <hip/hip_runtime.h>
#include <hip/hip_bf16.h>
#include <hip/hip_fp8.h>

#define N 8192
#define D 200
#define KP 232      // fp8 row stride BYTES: 58 dwords, gcd(58,32)=2 -> <=2-way LDS aliasing
#define NSTEP 7     // 7 * 32 = 224 K fed to MFMA
#define NB 64       // 8192 / 128 tiles per dim
#define NBLK 512    // 32 row-pairs x 16 strips; each block: 4-5 tiles
#define NPART (NBLK * 4)
#define PANEL (128 * KP)           // 29696 B, contiguous in global AND in LDS

typedef float f32x4 __attribute__((ext_vector_type(4)));
#define AS3 __attribute__((address_space(3)))
#define AS1 __attribute__((address_space(1)))

// ---- prep: cast to fp8 e4m3 (padded to KP), row norms from fp8-decoded ----
__global__ __launch_bounds__(256) void prep_kernel(
    const float* __restrict__ x, const int* __restrict__ labels,
    unsigned char* __restrict__ xb, float* __restrict__ sq,
    int* __restrict__ lab) {
  int row = blockIdx.x * 4 + (threadIdx.x >> 6);   // one wave per row
  int lane = threadIdx.x & 63;
  const float* xr = x + (size_t)row * D;
  unsigned char* xbr = xb + (size_t)row * KP;
  int k0 = lane * 4;
  float4 f = {0.f, 0.f, 0.f, 0.f};
  if (k0 < D) f = *(const float4*)(xr + k0);       // lane<50 fully in-bounds
  float s = 0.f;
  unsigned char q[4];
  float ff[4] = {f.x, f.y, f.z, f.w};
#pragma unroll
  for (int c = 0; c < 4; ++c) {
    float v = (k0 + c < D) ? ff[c] : 0.f;
    __hip_fp8_e4m3 h(v);                           // OCP e4m3 RNE
    q[c] = h.__x;
    float fb = (float)h;
    s += fb * fb;                                  // norm of the fp8-rounded row
  }
  if (k0 < KP) *(uchar4*)(xbr + k0) = *(uchar4*)q; // lanes 0..57 (56,57 write zeros)
#pragma unroll
  for (int m = 32; m; m >>= 1) s += __shfl_xor(s, m);
  if (lane == 0) {
    sq[row] = s;
    lab[row] = labels[row];
  }
}

// --- multi-tile fp8 MFMA: A-panel reuse, B staging overlapped with epilogue ---
__global__ __launch_bounds__(256) void gram_kernel(
    const unsigned char* __restrict__ xb, const float* __restrict__ sq,
    const int* __restrict__ lab, double* __restrict__ partial) {
  __shared__ __align__(16) unsigned char sA[PANEL];
  __shared__ __align__(16) unsigned char sB[PANEL];

  const int t = threadIdx.x;
  const int b = blockIdx.x;
  const int q = b >> 4, s = b & 15;                // row-pair q / strip s
  const int row2 = 63 - q;
  const int n1 = 64 - q;                           // tiles in row q; row2 has q+1; 65 total

  const int wid = t >> 6, lane = t & 63;
  const int col = lane & 15, quad = lane >> 4;
  const int waveM = (wid >> 1) * 64, waveN = (wid & 1) * 64;

  auto stage = [&](const unsigned char* g, unsigned char* sh) {
#pragma unroll
    for (int c = 0; c < 7; ++c) {
      int off = c * 4096 + t * 16;
      __builtin_amdgcn_global_load_lds((const AS1 void*)(g + off),
                                       (AS3 void*)(sh + off), 16, 0, 0);
    }
    if (t < 64) {
      int off = 28672 + t * 16;
      __builtin_amdgcn_global_load_lds((const AS1 void*)(g + off),
                                       (AS3 void*)(sh + off), 16, 0, 0);
    }
  };

  int idx = s;                                     // strided walk: s, s+16, ... < 65
  int bi = (idx < n1) ? q : row2;
  int bj = (idx < n1) ? q + idx : row2 + (idx - n1);
  stage(xb + (size_t)bi * PANEL, sA);
  stage(xb + (size_t)bj * PANEL, sB);
  __syncthreads();

  float tot = 0.f;
  while (true) {
    // ---- K-loop on (bi, bj) ----
    f32x4 acc[4][4] = {};
#pragma unroll
    for (int step = 0; step < NSTEP; ++step) {
      long a[4], bf[4];
#pragma unroll
      for (int mi = 0; mi < 4; ++mi)
        a[mi] = *(const long*)(sA + (waveM + mi * 16 + col) * KP + step * 32 + quad * 8);
#pragma unroll
      for (int ni = 0; ni < 4; ++ni)
        bf[ni] = *(const long*)(sB + (waveN + ni * 16 + col) * KP + step * 32 + quad * 8);
#pragma unroll
      for (int mi = 0; mi < 4; ++mi)
#pragma unroll
        for (int ni = 0; ni < 4; ++ni)
          acc[mi][ni] = __builtin_amdgcn_mfma_f32_16x16x32_fp8_fp8(
              a[mi], bf[ni], acc[mi][ni], 0, 0, 0);
    }
    __syncthreads();                               // all waves done reading sA/sB

    // ---- issue next tile's staging BEFORE the epilogue (overlap) ----
    const int nidx = idx + 16;
    const bool more = (nidx < 65);
    int nbi = 0, nbj = 0;
    if (more) {
      nbi = (nidx < n1) ? q : row2;
      nbj = (nidx < n1) ? q + nidx : row2 + (nidx - n1);
      if (nbi != bi) stage(xb + (size_t)nbi * PANEL, sA);   // rare: row switch
      stage(xb + (size_t)nbj * PANEL, sB);
    }

    // ---- epilogue (overlaps staging): D[m = quad*4 + r][n = col] ----
    const int i0 = bi * 128 + waveM, j0 = bj * 128 + waveN;
    int labj[4];
    float sqj[4];
#pragma unroll
    for (int ni = 0; ni < 4; ++ni) {
      int j = j0 + ni * 16 + col;
      labj[ni] = lab[j];
      sqj[ni] = sq[j];
    }
    float rs = 0.f;
    if (bi != bj) {
#pragma unroll
      for (int mi = 0; mi < 4; ++mi) {
#pragma unroll
        for (int r = 0; r < 4; ++r) {
          int i = i0 + mi * 16 + quad * 4 + r;
          float sqi = sq[i];
          int li = lab[i];
#pragma unroll
          for (int ni = 0; ni < 4; ++ni) {
            float g = acc[mi][ni][r];
            float d2 = fmaxf(fmaf(-2.f, g, sqi + sqj[ni]), 0.f);
            float dist = __builtin_amdgcn_sqrtf(d2);
            rs += (li == labj[ni]) ? dist : -dist;
          }
        }
      }
      tot += 2.f * rs;                             // mirror tile not launched
    } else {
#pragma unroll
      for (int mi = 0; mi < 4; ++mi) {
#pragma unroll
        for (int r = 0; r < 4; ++r) {
          int i = i0 + mi * 16 + quad * 4 + r;
          float sqi = sq[i];
          int li = lab[i];
#pragma unroll
          for (int ni = 0; ni < 4; ++ni) {
            int j = j0 + ni * 16 + col;
            float g = acc[mi][ni][r];
            float d2 = fmaxf(fmaf(-2.f, g, sqi + sqj[ni]), 0.f);
            float dist = __builtin_amdgcn_sqrtf(d2);
            float c = (li == labj[ni]) ? dist : -dist;
            rs += (i == j) ? 0.f : c;
          }
        }
      }
      tot += rs;
    }

    if (!more) break;
    bi = nbi; bj = nbj; idx = nidx;
    __syncthreads();                               // staging (vmcnt) drained here
  }

#pragma unroll
  for (int m = 32; m; m >>= 1) tot += __shfl_xor(tot, m);
  if (lane == 0) partial[b * 4 + wid] = (double)tot;
}

// ---------------- final mean ----------------
__global__ __launch_bounds__(256) void reduce_kernel(
    const double* __restrict__ partial, float* __restrict__ out) {
  __shared__ double wsum[4];
  double s = 0.0;
  for (int i = threadIdx.x; i < NPART; i += 256) s += partial[i];
#pragma unroll
  for (int m = 32; m; m >>= 1) s += __shfl_xor(s, m);
  if ((threadIdx.x & 63) == 0) wsum[threadIdx.x >> 6] = s;
  __syncthreads();
  if (threadIdx.x == 0)
    out[0] = (float)((wsum[0] + wsum[1] + wsum[2] + wsum[3]) / (double)N);
}

extern "C" void kernel_launch(void* const* d_in, const int* in_sizes, int n_in,
                              void* d_out, int out_size, void* d_ws, size_t ws_size,
                              hipStream_t stream) {
  const float* x = (const float*)d_in[0];
  const int* labels = (const int*)d_in[1];
  char* ws = (char*)d_ws;
  unsigned char* xb = (unsigned char*)ws;                            // N*KP = 1.9 MB
  float* sq = (float*)(ws + (size_t)N * KP);                         // N*4
  int* lab = (int*)(ws + (size_t)N * KP + (size_t)N * 4);            // N*4
  double* partial = (double*)(ws + (size_t)N * KP + (size_t)N * 8);  // NPART*8
  float* out = (float*)d_out;

  prep_kernel<<<N / 4, 256, 0, stream>>>(x, labels, xb, sq, lab);
  gram_kernel<<<NBLK, 256, 0, stream>>>(xb, sq, lab, partial);
  reduce_kernel<<<1, 256, 0, stream>>>(partial, out);
}